// Round 2
// baseline (576.267 us; speedup 1.0000x reference)
//
#include <hip/hip_runtime.h>

#define NB 32
#define ND 64
#define NT 4096
#define NK 512
#define NN (NB*NT)

// ---------------------------------------------------------------------------
// enorm[k] = numpy-pairwise sum of codebook[k,:]^2  (n=64 -> 8-accumulator
// pattern, square rounded before add; no FMA contraction).
// ---------------------------------------------------------------------------
__global__ void enorm_kernel(const float* __restrict__ cb, float* __restrict__ enorm) {
    int k = blockIdx.x * blockDim.x + threadIdx.x;
    if (k >= NK) return;
    const float* e = cb + (size_t)k * ND;
    float r[8];
#pragma unroll
    for (int j = 0; j < 8; ++j) {
        float s = __fmul_rn(e[j], e[j]);
#pragma unroll
        for (int i = 1; i < 8; ++i) {
            float p = __fmul_rn(e[8 * i + j], e[8 * i + j]);
            s = __fadd_rn(s, p);
        }
        r[j] = s;
    }
    float res = __fadd_rn(__fadd_rn(__fadd_rn(r[0], r[1]), __fadd_rn(r[2], r[3])),
                          __fadd_rn(__fadd_rn(r[4], r[5]), __fadd_rn(r[6], r[7])));
    enorm[k] = res;
}

// ---------------------------------------------------------------------------
// Main kernel, K-split x2 for occupancy:
//   block = 256 threads = 128 rows x 2 k-chunks (chunk c scans k in
//   [c*256, c*256+256)). Waves 0-1: chunk 0, waves 2-3: chunk 1, same rows.
//   Combine argmin via LDS (chunk0 wins ties -> numpy first-occurrence).
//   Epilogue: thread (rl, c) writes d in [c*32, c*32+32) for row rl.
// Exactness: per-code dot = sequential ascending-d fp32 fmaf chain (BLAS
// order); dist = (zn + enorm_k) - 2*dot with exactly one rounding per op.
// ---------------------------------------------------------------------------
__global__ __launch_bounds__(256, 4) void vq_main(const float* __restrict__ z,
                                                  const float* __restrict__ cb,
                                                  const float* __restrict__ enorm,
                                                  float* __restrict__ qout,
                                                  float* __restrict__ idxout,
                                                  double* __restrict__ loss_acc) {
    const int bi    = blockIdx.x;
    const int b     = bi >> 5;               // 32 t-tiles of 128 per b
    const int tbase = (bi & 31) * 128;
    const int tid   = threadIdx.x;
    const int rl    = tid & 127;             // row-in-block
    const int c     = tid >> 7;              // k-chunk (0/1), also d-half in epilogue
    const int t     = tbase + rl;

    const float* zp = z + (size_t)b * (ND * NT) + t;   // stride NT per d
    float zv[ND];
#pragma unroll
    for (int d = 0; d < ND; ++d) zv[d] = zp[(size_t)d * NT];

    // znorm: numpy pairwise pattern (rounded squares, sequential 8-acc)
    float r[8];
#pragma unroll
    for (int j = 0; j < 8; ++j) {
        float s = __fmul_rn(zv[j], zv[j]);
#pragma unroll
        for (int i = 1; i < 8; ++i) {
            float p = __fmul_rn(zv[8 * i + j], zv[8 * i + j]);
            s = __fadd_rn(s, p);
        }
        r[j] = s;
    }
    const float zn = __fadd_rn(__fadd_rn(__fadd_rn(r[0], r[1]), __fadd_rn(r[2], r[3])),
                               __fadd_rn(__fadd_rn(r[4], r[5]), __fadd_rn(r[6], r[7])));

    float best = __builtin_inff();
    int   bidx = c * 256;

    const float* cbp = cb + (size_t)c * 256 * ND;
    const float* enp = enorm + c * 256;

    for (int kk = 0; kk < 256; kk += 8) {
        const float* e = cbp + (size_t)kk * ND;
        float acc[8];
#pragma unroll
        for (int j = 0; j < 8; ++j) acc[j] = 0.0f;
#pragma unroll
        for (int d = 0; d < ND; ++d) {
            const float zd = zv[d];
#pragma unroll
            for (int j = 0; j < 8; ++j)
                acc[j] = __builtin_fmaf(zd, e[(size_t)j * ND + d], acc[j]);
        }
#pragma unroll
        for (int j = 0; j < 8; ++j) {
            const float Dv = __fsub_rn(__fadd_rn(zn, enp[kk + j]), __fmul_rn(2.0f, acc[j]));
            if (Dv < best) { best = Dv; bidx = c * 256 + kk + j; }
        }
    }

    // ---- combine the two chunks (chunk0 wins ties = lowest k first) ----
    __shared__ float sbest1[128];
    __shared__ int   sidx1[128];
    __shared__ int   sidx[128];
    if (c == 1) { sbest1[rl] = best; sidx1[rl] = bidx; }
    __syncthreads();
    if (c == 0) {
        const float b1 = sbest1[rl];
        if (b1 < best) { best = b1; bidx = sidx1[rl]; }
        sidx[rl] = bidx;
        idxout[(size_t)b * NT + t] = (float)bidx;
    }
    __syncthreads();

    // ---- epilogue: straight-through out + loss; thread covers d-half c ----
    const int    fidx = sidx[rl];
    const float* e    = cb + (size_t)fidx * ND + c * 32;
    float*       qp   = qout + (size_t)b * (ND * NT) + t;
    double lsum = 0.0;
    const float4* e4 = (const float4*)e;     // cb row 256B-aligned, +128B ok
#pragma unroll
    for (int i = 0; i < 8; ++i) {
        const float4 ev = e4[i];
        const int d0 = c * 32 + i * 4;
        const float evs[4] = {ev.x, ev.y, ev.z, ev.w};
#pragma unroll
        for (int q = 0; q < 4; ++q) {
            const int   d    = d0 + q;
            const float diff = __fsub_rn(evs[q], zv[d]);   // quantized - zt
            const float qs   = __fadd_rn(zv[d], diff);     // zt + (q - zt)
            qp[(size_t)d * NT] = qs;
            lsum += (double)diff * (double)diff;
        }
    }

    // block reduce lsum -> one atomic per block
#pragma unroll
    for (int off = 32; off > 0; off >>= 1) lsum += __shfl_down(lsum, off, 64);
    __shared__ double sred[4];
    if ((tid & 63) == 0) sred[tid >> 6] = lsum;
    __syncthreads();
    if (tid == 0) {
        atomicAdd(loss_acc, (sred[0] + sred[1]) + (sred[2] + sred[3]));
    }
}

__global__ void finalize_kernel(const double* __restrict__ loss_acc,
                                float* __restrict__ out0) {
    // vq_loss = m + 0.25*m = 1.25*m,  m = sum / (B*T*D)
    double m = loss_acc[0] / (double)((size_t)NB * NT * ND);
    out0[0] = (float)(1.25 * m);
}

extern "C" void kernel_launch(void* const* d_in, const int* in_sizes, int n_in,
                              void* d_out, int out_size, void* d_ws, size_t ws_size,
                              hipStream_t stream) {
    const float* z  = (const float*)d_in[0];
    const float* cb = (const float*)d_in[1];

    float* out      = (float*)d_out;
    float* loss_out = out;                                  // 1 elem
    float* qout     = out + 1;                              // B*D*T elems
    float* idxout   = out + 1 + (size_t)NB * ND * NT;       // B*T elems

    double* loss_acc = (double*)d_ws;
    float*  enorm    = (float*)((char*)d_ws + 16);

    hipMemsetAsync(d_ws, 0, 16, stream);
    enorm_kernel<<<1, 512, 0, stream>>>(cb, enorm);
    vq_main<<<1024, 256, 0, stream>>>(z, cb, enorm, qout, idxout, loss_acc);
    finalize_kernel<<<1, 1, 0, stream>>>(loss_acc, loss_out);
}

// Round 3
// 574.808 us; speedup vs baseline: 1.0025x; 1.0025x over previous
//
#include <hip/hip_runtime.h>

#define NB 32
#define ND 64
#define NT 4096
#define NK 512
#define NN (NB*NT)

// ---------------------------------------------------------------------------
// enorm[k] = numpy-pairwise sum of codebook[k,:]^2  (n=64 -> 8-accumulator
// pattern, square rounded before add; no FMA contraction).
// ---------------------------------------------------------------------------
__global__ void enorm_kernel(const float* __restrict__ cb, float* __restrict__ enorm) {
    int k = blockIdx.x * blockDim.x + threadIdx.x;
    if (k >= NK) return;
    const float* e = cb + (size_t)k * ND;
    float r[8];
#pragma unroll
    for (int j = 0; j < 8; ++j) {
        float s = __fmul_rn(e[j], e[j]);
#pragma unroll
        for (int i = 1; i < 8; ++i) {
            float p = __fmul_rn(e[8 * i + j], e[8 * i + j]);
            s = __fadd_rn(s, p);
        }
        r[j] = s;
    }
    float res = __fadd_rn(__fadd_rn(__fadd_rn(r[0], r[1]), __fadd_rn(r[2], r[3])),
                          __fadd_rn(__fadd_rn(r[4], r[5]), __fadd_rn(r[6], r[7])));
    enorm[k] = res;
}

// ---------------------------------------------------------------------------
// Main kernel, K-split x2 for occupancy. __launch_bounds__(256, 2): min-waves
// 2/EU -> VGPR cap 256, so zv[64] stays register-resident (R2's (256,4)
// forced a 64-VGPR cap -> 67 MB of scratch spill traffic -> 523 us).
//   block = 256 threads = 128 rows x 2 k-chunks (chunk c scans k in
//   [c*256, c*256+256)). Combine argmin via LDS (chunk0 wins ties -> numpy
//   first-occurrence). Epilogue: thread (rl, c) writes d in [c*32, c*32+32).
// Exactness: per-code dot = sequential ascending-d fp32 fmaf chain (BLAS
// order); dist = (zn + enorm_k) - 2*dot with exactly one rounding per op.
// Verified absmax = 0.0 in R1/R2.
// ---------------------------------------------------------------------------
__global__ __launch_bounds__(256, 2) void vq_main(const float* __restrict__ z,
                                                  const float* __restrict__ cb,
                                                  const float* __restrict__ enorm,
                                                  float* __restrict__ qout,
                                                  float* __restrict__ idxout,
                                                  double* __restrict__ loss_acc) {
    const int bi    = blockIdx.x;
    const int b     = bi >> 5;               // 32 t-tiles of 128 per b
    const int tbase = (bi & 31) * 128;
    const int tid   = threadIdx.x;
    const int rl    = tid & 127;             // row-in-block
    const int c     = tid >> 7;              // k-chunk (0/1), also d-half in epilogue
    const int t     = tbase + rl;

    const float* zp = z + (size_t)b * (ND * NT) + t;   // stride NT per d
    float zv[ND];
#pragma unroll
    for (int d = 0; d < ND; ++d) zv[d] = zp[(size_t)d * NT];

    // znorm: numpy pairwise pattern (rounded squares, sequential 8-acc)
    float r[8];
#pragma unroll
    for (int j = 0; j < 8; ++j) {
        float s = __fmul_rn(zv[j], zv[j]);
#pragma unroll
        for (int i = 1; i < 8; ++i) {
            float p = __fmul_rn(zv[8 * i + j], zv[8 * i + j]);
            s = __fadd_rn(s, p);
        }
        r[j] = s;
    }
    const float zn = __fadd_rn(__fadd_rn(__fadd_rn(r[0], r[1]), __fadd_rn(r[2], r[3])),
                               __fadd_rn(__fadd_rn(r[4], r[5]), __fadd_rn(r[6], r[7])));

    float best = __builtin_inff();
    int   bidx = c * 256;

    const float* cbp = cb + (size_t)c * 256 * ND;
    const float* enp = enorm + c * 256;

    for (int kk = 0; kk < 256; kk += 8) {
        const float* e = cbp + (size_t)kk * ND;
        float acc[8];
#pragma unroll
        for (int j = 0; j < 8; ++j) acc[j] = 0.0f;
#pragma unroll
        for (int d = 0; d < ND; ++d) {
            const float zd = zv[d];
#pragma unroll
            for (int j = 0; j < 8; ++j)
                acc[j] = __builtin_fmaf(zd, e[(size_t)j * ND + d], acc[j]);
        }
#pragma unroll
        for (int j = 0; j < 8; ++j) {
            const float Dv = __fsub_rn(__fadd_rn(zn, enp[kk + j]), __fmul_rn(2.0f, acc[j]));
            if (Dv < best) { best = Dv; bidx = c * 256 + kk + j; }
        }
    }

    // ---- combine the two chunks (chunk0 wins ties = lowest k first) ----
    __shared__ float sbest1[128];
    __shared__ int   sidx1[128];
    __shared__ int   sidx[128];
    if (c == 1) { sbest1[rl] = best; sidx1[rl] = bidx; }
    __syncthreads();
    if (c == 0) {
        const float b1 = sbest1[rl];
        if (b1 < best) { best = b1; bidx = sidx1[rl]; }
        sidx[rl] = bidx;
        idxout[(size_t)b * NT + t] = (float)bidx;
    }
    __syncthreads();

    // ---- epilogue: straight-through out + loss; thread covers d-half c ----
    const int    fidx = sidx[rl];
    const float* e    = cb + (size_t)fidx * ND + c * 32;
    float*       qp   = qout + (size_t)b * (ND * NT) + t;
    double lsum = 0.0;
    const float4* e4 = (const float4*)e;     // cb row 256B-aligned, +128B ok
#pragma unroll
    for (int i = 0; i < 8; ++i) {
        const float4 ev = e4[i];
        const int d0 = c * 32 + i * 4;
        const float evs[4] = {ev.x, ev.y, ev.z, ev.w};
#pragma unroll
        for (int q = 0; q < 4; ++q) {
            const int   d    = d0 + q;
            const float diff = __fsub_rn(evs[q], zv[d]);   // quantized - zt
            const float qs   = __fadd_rn(zv[d], diff);     // zt + (q - zt)
            qp[(size_t)d * NT] = qs;
            lsum += (double)diff * (double)diff;
        }
    }

    // block reduce lsum -> one atomic per block
#pragma unroll
    for (int off = 32; off > 0; off >>= 1) lsum += __shfl_down(lsum, off, 64);
    __shared__ double sred[4];
    if ((tid & 63) == 0) sred[tid >> 6] = lsum;
    __syncthreads();
    if (tid == 0) {
        atomicAdd(loss_acc, (sred[0] + sred[1]) + (sred[2] + sred[3]));
    }
}

__global__ void finalize_kernel(const double* __restrict__ loss_acc,
                                float* __restrict__ out0) {
    // vq_loss = m + 0.25*m = 1.25*m,  m = sum / (B*T*D)
    double m = loss_acc[0] / (double)((size_t)NB * NT * ND);
    out0[0] = (float)(1.25 * m);
}

extern "C" void kernel_launch(void* const* d_in, const int* in_sizes, int n_in,
                              void* d_out, int out_size, void* d_ws, size_t ws_size,
                              hipStream_t stream) {
    const float* z  = (const float*)d_in[0];
    const float* cb = (const float*)d_in[1];

    float* out      = (float*)d_out;
    float* loss_out = out;                                  // 1 elem
    float* qout     = out + 1;                              // B*D*T elems
    float* idxout   = out + 1 + (size_t)NB * ND * NT;       // B*T elems

    double* loss_acc = (double*)d_ws;
    float*  enorm    = (float*)((char*)d_ws + 16);

    hipMemsetAsync(d_ws, 0, 16, stream);
    enorm_kernel<<<1, 512, 0, stream>>>(cb, enorm);
    vq_main<<<1024, 256, 0, stream>>>(z, cb, enorm, qout, idxout, loss_acc);
    finalize_kernel<<<1, 1, 0, stream>>>(loss_acc, loss_out);
}

// Round 4
// 261.696 us; speedup vs baseline: 2.2020x; 2.1965x over previous
//
#include <hip/hip_runtime.h>

#define NB 32
#define ND 64
#define NT 4096
#define NK 512
#define NN (NB*NT)

// ---------------------------------------------------------------------------
// enorm[k] = numpy-pairwise sum of codebook[k,:]^2 (verified bit-exact R1-R3).
// ---------------------------------------------------------------------------
__global__ void enorm_kernel(const float* __restrict__ cb, float* __restrict__ enorm) {
    int k = blockIdx.x * blockDim.x + threadIdx.x;
    if (k >= NK) return;
    const float* e = cb + (size_t)k * ND;
    float r[8];
#pragma unroll
    for (int j = 0; j < 8; ++j) {
        float s = __fmul_rn(e[j], e[j]);
#pragma unroll
        for (int i = 1; i < 8; ++i) {
            float p = __fmul_rn(e[8 * i + j], e[8 * i + j]);
            s = __fadd_rn(s, p);
        }
        r[j] = s;
    }
    enorm[k] = __fadd_rn(__fadd_rn(__fadd_rn(r[0], r[1]), __fadd_rn(r[2], r[3])),
                         __fadd_rn(__fadd_rn(r[4], r[5]), __fadd_rn(r[6], r[7])));
}

// ---------------------------------------------------------------------------
// Main kernel R4: z tile in LDS (d-major pairs), no per-thread z[64] array
// (R2/R3's runtime-indexed private array forced 67 MB scratch spill).
//   block = 256 thr = 64 rows x 4 wave-chunks; wave wv scans codes
//   [wv*128, wv*128+128). Chunk id via readfirstlane -> codebook stays
//   scalar-loaded. zs2[p][row]: ds_read_b64 serves 2 d's (1 LDS instr per
//   16 fmaf; conflict-free, lanes consecutive).
// Exactness (verified absmax=0 in R1-R3): dot = ascending-d fp32 fmaf chain;
// dist = (zn + e_k) - 2*dot, one rounding per op; argmin strict < ascending k
// (cross-chunk combine ascending chunk, strict <).
// ---------------------------------------------------------------------------
__global__ __launch_bounds__(256) void vq_main(const float* __restrict__ z,
                                               const float* __restrict__ cb,
                                               const float* __restrict__ enorm,
                                               float* __restrict__ qout,
                                               float* __restrict__ idxout,
                                               double* __restrict__ loss_acc) {
    const int bi    = blockIdx.x;
    const int b     = bi >> 6;             // 64 t-tiles of 64 rows per b
    const int tbase = (bi & 63) * 64;
    const int tid   = threadIdx.x;
    const int rl    = tid & 63;            // row-in-block == lane
    const int wv    = __builtin_amdgcn_readfirstlane(tid >> 6);  // wave/chunk id

    __shared__ float2 zs2[32 * 64];        // [d-pair p][row]: (z[2p][r], z[2p+1][r])
    __shared__ float  sbst[4][64];
    __shared__ int    sidx[4][64];
    __shared__ int    sfin[64];
    __shared__ double sred[4];

    // ---- stage z tile: global [b][d][tbase+i] -> zs2[d>>1][i].{x,y} ----
    const size_t zoff = (size_t)b * (ND * NT) + tbase;
    float* zsf = (float*)zs2;              // flat dwords: (p*64 + row)*2 + (d&1)
#pragma unroll
    for (int j = 0; j < 4; ++j) {
        const int q  = j * 256 + tid;      // float4 id 0..1023
        const int d  = q >> 4;             // 16 float4 per d-row
        const int i4 = q & 15;
        const float4 v = *(const float4*)(z + zoff + (size_t)d * NT + i4 * 4);
        const int p = d >> 1, par = d & 1;
        zsf[(p * 64 + (i4 * 4 + 0)) * 2 + par] = v.x;
        zsf[(p * 64 + (i4 * 4 + 1)) * 2 + par] = v.y;
        zsf[(p * 64 + (i4 * 4 + 2)) * 2 + par] = v.z;
        zsf[(p * 64 + (i4 * 4 + 3)) * 2 + par] = v.w;
    }
    __syncthreads();

    // ---- znorm: numpy pairwise (8 accumulators over d = 8i+j) ----
    float r[8];
#pragma unroll
    for (int i = 0; i < 8; ++i) {
        float v[8];
#pragma unroll
        for (int pp = 0; pp < 4; ++pp) {
            const float2 t2 = zs2[(i * 4 + pp) * 64 + rl];
            v[2 * pp]     = t2.x;
            v[2 * pp + 1] = t2.y;
        }
#pragma unroll
        for (int jj = 0; jj < 8; ++jj) {
            const float sq = __fmul_rn(v[jj], v[jj]);
            r[jj] = (i == 0) ? sq : __fadd_rn(r[jj], sq);
        }
    }
    const float zn = __fadd_rn(__fadd_rn(__fadd_rn(r[0], r[1]), __fadd_rn(r[2], r[3])),
                               __fadd_rn(__fadd_rn(r[4], r[5]), __fadd_rn(r[6], r[7])));

    // ---- k-loop: this wave's 128-code chunk, groups of 8 ----
    const float* cbp = cb + (size_t)wv * 128 * ND;
    const float* enp = enorm + wv * 128;
    float best = __builtin_inff();
    int   bidx = wv * 128;

    for (int kk = 0; kk < 128; kk += 8) {
        const float* e = cbp + (size_t)kk * ND;
        float acc[8];
#pragma unroll
        for (int jj = 0; jj < 8; ++jj) acc[jj] = 0.0f;
#pragma unroll
        for (int dp = 0; dp < 32; ++dp) {
            const float2 zp = zs2[dp * 64 + rl];   // ds_read_b64, conflict-free
#pragma unroll
            for (int jj = 0; jj < 8; ++jj)
                acc[jj] = __builtin_fmaf(zp.x, e[(size_t)jj * ND + 2 * dp], acc[jj]);
#pragma unroll
            for (int jj = 0; jj < 8; ++jj)
                acc[jj] = __builtin_fmaf(zp.y, e[(size_t)jj * ND + 2 * dp + 1], acc[jj]);
        }
#pragma unroll
        for (int jj = 0; jj < 8; ++jj) {
            const float Dv = __fsub_rn(__fadd_rn(zn, enp[kk + jj]),
                                       __fmul_rn(2.0f, acc[jj]));
            if (Dv < best) { best = Dv; bidx = wv * 128 + kk + jj; }
        }
    }

    // ---- combine 4 chunks (ascending chunk + strict < = first occurrence) ----
    sbst[wv][rl] = best;
    sidx[wv][rl] = bidx;
    __syncthreads();
    if (wv == 0) {
        float bb = sbst[0][rl];
        int   bx = sidx[0][rl];
#pragma unroll
        for (int c = 1; c < 4; ++c) {
            const float o = sbst[c][rl];
            if (o < bb) { bb = o; bx = sidx[c][rl]; }
        }
        sfin[rl] = bx;
        idxout[(size_t)b * NT + tbase + rl] = (float)bx;
    }
    __syncthreads();

    // ---- epilogue: wave wv covers d in [wv*16, wv*16+16) for all 64 rows ----
    const int    fidx = sfin[rl];
    const int    d0   = wv * 16;
    const float* e    = cb + (size_t)fidx * ND + d0;   // per-lane gather (L2-hot)
    float*       qp   = qout + zoff;
    double lsum = 0.0;
#pragma unroll
    for (int u = 0; u < 8; ++u) {
        const float2 zp = zs2[(d0 / 2 + u) * 64 + rl];
        const float2 ev = *(const float2*)(e + 2 * u);
        const int d = d0 + 2 * u;
        const float diff0 = __fsub_rn(ev.x, zp.x);     // quantized - zt
        qp[(size_t)d * NT + rl] = __fadd_rn(zp.x, diff0);
        lsum += (double)diff0 * (double)diff0;
        const float diff1 = __fsub_rn(ev.y, zp.y);
        qp[(size_t)(d + 1) * NT + rl] = __fadd_rn(zp.y, diff1);
        lsum += (double)diff1 * (double)diff1;
    }

    // ---- loss: wave shuffle-reduce -> LDS -> one atomic per block ----
#pragma unroll
    for (int off = 32; off > 0; off >>= 1) lsum += __shfl_down(lsum, off, 64);
    if (rl == 0) sred[wv] = lsum;
    __syncthreads();
    if (tid == 0)
        atomicAdd(loss_acc, (sred[0] + sred[1]) + (sred[2] + sred[3]));
}

__global__ void finalize_kernel(const double* __restrict__ loss_acc,
                                float* __restrict__ out0) {
    // vq_loss = m + 0.25*m = 1.25*m,  m = sum / (B*T*D)
    double m = loss_acc[0] / (double)((size_t)NB * NT * ND);
    out0[0] = (float)(1.25 * m);
}

extern "C" void kernel_launch(void* const* d_in, const int* in_sizes, int n_in,
                              void* d_out, int out_size, void* d_ws, size_t ws_size,
                              hipStream_t stream) {
    const float* z  = (const float*)d_in[0];
    const float* cb = (const float*)d_in[1];

    float* out      = (float*)d_out;
    float* loss_out = out;                                  // 1 elem
    float* qout     = out + 1;                              // B*D*T elems
    float* idxout   = out + 1 + (size_t)NB * ND * NT;       // B*T elems

    double* loss_acc = (double*)d_ws;
    float*  enorm    = (float*)((char*)d_ws + 16);

    hipMemsetAsync(d_ws, 0, 16, stream);
    enorm_kernel<<<1, 512, 0, stream>>>(cb, enorm);
    vq_main<<<2048, 256, 0, stream>>>(z, cb, enorm, qout, idxout, loss_acc);
    finalize_kernel<<<1, 1, 0, stream>>>(loss_acc, loss_out);
}

// Round 5
// 200.938 us; speedup vs baseline: 2.8679x; 1.3024x over previous
//
#include <hip/hip_runtime.h>

#define NB 32
#define ND 64
#define NT 4096
#define NK 512

// ---------------------------------------------------------------------------
// R5: register-tiled "GEMM" structure. Block = 256 thr = 16 rg x 16 cg.
// Thread tile: 8 rows x 8 codes (64 fp32 acc). z tile (128 rows) and e chunk
// (128 codes) both in LDS, rows permuted perm(r)=(r&7)*16+(r>>3), stride 68
// dwords, so concurrent b128 reads are ~conflict-free. No scalar codebook
// path (R4's stall). enorm computed in-block; loss via per-block partials.
// Exactness (absmax=0.0 R1-R4): dot = ascending-d fp32 fmaf chain; pairwise
// norms; dist=(zn+en)-2*dot one rounding/op; argmin = first occurrence via
// ascending-k strict < within thread + lexicographic (dist,idx) across.
// ---------------------------------------------------------------------------
#define STR 68
#define SM_ZL   0                    // 128*68*4 = 34816 B
#define SM_EL   34816                // 128*68*4 = 34816 B (reused for reduce)
#define SM_ZNL  69632                // 128*4
#define SM_ENL  70144                // 128*4
#define SM_SFIN 70656                // 128*4
#define SM_SRED 71168                // 4*8
#define SM_SIZE 71200

__global__ __launch_bounds__(256) void vq_main(const float* __restrict__ z,
                                               const float* __restrict__ cb,
                                               float* __restrict__ qout,
                                               float* __restrict__ idxout,
                                               double* __restrict__ partials) {
    __shared__ __align__(16) char smem[SM_SIZE];
    float*  zl   = (float*)(smem + SM_ZL);
    float*  el   = (float*)(smem + SM_EL);
    float*  znl  = (float*)(smem + SM_ZNL);
    float*  enl  = (float*)(smem + SM_ENL);
    int*    sfin = (int*)(smem + SM_SFIN);
    double* sred = (double*)(smem + SM_SRED);

    const int bi    = blockIdx.x;          // 1024 blocks
    const int b     = bi >> 5;             // 32 t-tiles of 128 rows per b
    const int tbase = (bi & 31) * 128;
    const int tid   = threadIdx.x;
    const int rg    = tid >> 4;            // row-group 0..15 (rows rg*8..+7)
    const int cg    = tid & 15;            // code-group 0..15

    const size_t zoff = (size_t)b * (ND * NT) + tbase;

    // ---- stage z: global [d][t] -> zl[perm(r)*STR + d] (transpose) ----
#pragma unroll
    for (int j = 0; j < 8; ++j) {
        const int q  = j * 256 + tid;      // float4 id: 64 d-rows x 32 quads
        const int i4 = q & 31, d = q >> 5;
        const float4 v = *(const float4*)(z + zoff + (size_t)d * NT + i4 * 4);
        const float vv[4] = {v.x, v.y, v.z, v.w};
#pragma unroll
        for (int c = 0; c < 4; ++c) {
            const int r = i4 * 4 + c;
            zl[((r & 7) * 16 + (r >> 3)) * STR + d] = vv[c];
        }
    }
    __syncthreads();

    // ---- znorm rows 0..127 (numpy pairwise, threads 0..127) ----
    if (tid < 128) {
        const int r = tid;
        const float4* zr4 = (const float4*)&zl[((r & 7) * 16 + (r >> 3)) * STR];
        float x[64];
#pragma unroll
        for (int w = 0; w < 16; ++w) {
            const float4 t4 = zr4[w];
            x[4*w] = t4.x; x[4*w+1] = t4.y; x[4*w+2] = t4.z; x[4*w+3] = t4.w;
        }
        float r8[8];
#pragma unroll
        for (int jj = 0; jj < 8; ++jj) {
            float s = __fmul_rn(x[jj], x[jj]);
#pragma unroll
            for (int ii = 1; ii < 8; ++ii)
                s = __fadd_rn(s, __fmul_rn(x[8*ii+jj], x[8*ii+jj]));
            r8[jj] = s;
        }
        znl[r] = __fadd_rn(__fadd_rn(__fadd_rn(r8[0],r8[1]), __fadd_rn(r8[2],r8[3])),
                           __fadd_rn(__fadd_rn(r8[4],r8[5]), __fadd_rn(r8[6],r8[7])));
    }
    __syncthreads();

    float znr[8];
#pragma unroll
    for (int i = 0; i < 8; ++i) znr[i] = znl[rg * 8 + i];

    float bst[8]; int bix[8];
#pragma unroll
    for (int i = 0; i < 8; ++i) { bst[i] = __builtin_inff(); bix[i] = 0; }

    for (int cc = 0; cc < 4; ++cc) {
        __syncthreads();                   // el readers of prev chunk done
        // ---- stage e chunk: cb[cc*128+kl][:] -> el[perm(kl)*STR + d] ----
#pragma unroll
        for (int j = 0; j < 8; ++j) {
            const int q  = j * 256 + tid;  // 128 codes x 16 quads
            const int kl = q >> 4, d4 = q & 15;
            const float4 v = *(const float4*)(cb + (size_t)(cc * 128 + kl) * ND + d4 * 4);
            *(float4*)&el[((kl & 7) * 16 + (kl >> 3)) * STR + d4 * 4] = v;
        }
        __syncthreads();
        // ---- enorm for this chunk (numpy pairwise, from el) ----
        if (tid < 128) {
            const int kl = tid;
            const float* ep = &el[((kl & 7) * 16 + (kl >> 3)) * STR];
            float r8[8];
#pragma unroll
            for (int jj = 0; jj < 8; ++jj) {
                float s = __fmul_rn(ep[jj], ep[jj]);
#pragma unroll
                for (int ii = 1; ii < 8; ++ii)
                    s = __fadd_rn(s, __fmul_rn(ep[8*ii+jj], ep[8*ii+jj]));
                r8[jj] = s;
            }
            enl[kl] = __fadd_rn(__fadd_rn(__fadd_rn(r8[0],r8[1]), __fadd_rn(r8[2],r8[3])),
                                __fadd_rn(__fadd_rn(r8[4],r8[5]), __fadd_rn(r8[6],r8[7])));
        }
        __syncthreads();

        float enr[8];
#pragma unroll
        for (int jj = 0; jj < 8; ++jj) enr[jj] = enl[cg * 8 + jj];

        float acc[8][8];
#pragma unroll
        for (int i = 0; i < 8; ++i)
#pragma unroll
            for (int jj = 0; jj < 8; ++jj) acc[i][jj] = 0.0f;

        const float* zb = zl + rg * STR;   // row i at +i*16*STR
        const float* eb = el + cg * STR;   // code j at +j*16*STR
#pragma unroll 2
        for (int dd = 0; dd < 64; dd += 4) {
            float4 zr[8], er[8];
#pragma unroll
            for (int i = 0; i < 8; ++i)  zr[i]  = *(const float4*)(zb + i  * (16*STR) + dd);
#pragma unroll
            for (int jj = 0; jj < 8; ++jj) er[jj] = *(const float4*)(eb + jj * (16*STR) + dd);
#pragma unroll
            for (int i = 0; i < 8; ++i) {
#pragma unroll
                for (int jj = 0; jj < 8; ++jj) {
                    float a = acc[i][jj];
                    a = __builtin_fmaf(zr[i].x, er[jj].x, a);
                    a = __builtin_fmaf(zr[i].y, er[jj].y, a);
                    a = __builtin_fmaf(zr[i].z, er[jj].z, a);
                    a = __builtin_fmaf(zr[i].w, er[jj].w, a);
                    acc[i][jj] = a;
                }
            }
        }
        // ---- dists + argmin (ascending k within thread -> strict <) ----
#pragma unroll
        for (int i = 0; i < 8; ++i) {
#pragma unroll
            for (int jj = 0; jj < 8; ++jj) {
                const float Dv = __fsub_rn(__fadd_rn(znr[i], enr[jj]),
                                           __fmul_rn(2.0f, acc[i][jj]));
                if (Dv < bst[i]) { bst[i] = Dv; bix[i] = cc * 128 + cg * 8 + jj; }
            }
        }
    }

    // ---- cross-thread argmin combine (lexicographic) — reuse el ----
    __syncthreads();
    float* fb = el;                        // [16][130]
    int*   fi = (int*)(el + 2080);
#pragma unroll
    for (int i = 0; i < 8; ++i) {
        const int r = rg * 8 + i;
        fb[cg * 130 + r] = bst[i];
        fi[cg * 130 + r] = bix[i];
    }
    __syncthreads();
    if (tid < 128) {
        const int r = tid;
        float bb = fb[r]; int bx = fi[r];
#pragma unroll
        for (int c = 1; c < 16; ++c) {
            const float o  = fb[c * 130 + r];
            const int   oi = fi[c * 130 + r];
            if (o < bb || (o == bb && oi < bx)) { bb = o; bx = oi; }
        }
        sfin[r] = bx;
        idxout[(size_t)b * NT + tbase + r] = (float)bx;
    }
    __syncthreads();

    // ---- epilogue: straight-through output + loss ----
    double lsum = 0.0;
#pragma unroll 4
    for (int j = 0; j < 32; ++j) {
        const int q  = j * 256 + tid;
        const int ir = q & 127, d = q >> 7;
        const float zv = zl[((ir & 7) * 16 + (ir >> 3)) * STR + d];
        const float ev = cb[(size_t)sfin[ir] * ND + d];     // L2-hot gather
        const float diff = __fsub_rn(ev, zv);               // quantized - zt
        qout[(size_t)b * (ND * NT) + (size_t)d * NT + tbase + ir] = __fadd_rn(zv, diff);
        lsum += (double)diff * (double)diff;
    }
#pragma unroll
    for (int off = 32; off > 0; off >>= 1) lsum += __shfl_down(lsum, off, 64);
    if ((tid & 63) == 0) sred[tid >> 6] = lsum;
    __syncthreads();
    if (tid == 0) partials[bi] = (sred[0] + sred[1]) + (sred[2] + sred[3]);
}

__global__ void finalize_kernel(const double* __restrict__ partials,
                                float* __restrict__ out0) {
    __shared__ double sred[4];
    const int tid = threadIdx.x;
    double s = partials[tid] + partials[tid + 256] + partials[tid + 512] + partials[tid + 768];
#pragma unroll
    for (int off = 32; off > 0; off >>= 1) s += __shfl_down(s, off, 64);
    if ((tid & 63) == 0) sred[tid >> 6] = s;
    __syncthreads();
    if (tid == 0) {
        const double m = ((sred[0] + sred[1]) + (sred[2] + sred[3]))
                         / (double)((size_t)NB * NT * ND);
        out0[0] = (float)(1.25 * m);       // codebook + 0.25*commitment
    }
}

extern "C" void kernel_launch(void* const* d_in, const int* in_sizes, int n_in,
                              void* d_out, int out_size, void* d_ws, size_t ws_size,
                              hipStream_t stream) {
    const float* z  = (const float*)d_in[0];
    const float* cb = (const float*)d_in[1];

    float* out      = (float*)d_out;
    float* loss_out = out;                                  // 1 elem
    float* qout     = out + 1;                              // B*D*T elems
    float* idxout   = out + 1 + (size_t)NB * ND * NT;       // B*T elems

    double* partials = (double*)d_ws;                       // 1024 doubles

    vq_main<<<1024, 256, 0, stream>>>(z, cb, qout, idxout, partials);
    finalize_kernel<<<1, 256, 0, stream>>>(partials, loss_out);
}